// Round 3
// baseline (12457.565 us; speedup 1.0000x reference)
//
#include <hip/hip_runtime.h>
#include <cstdint>
#include <cstddef>

#define VSZ 32000
#define ED  512
#define HD  512
#define SQ  128
#define BA  64
#define INW 1024
#define NG  1536
#define NWG 256

typedef __attribute__((ext_vector_type(8))) short sh8;
typedef __attribute__((ext_vector_type(4))) float f32x4;

__device__ inline unsigned short f2bf(float f) {
  unsigned int u = __float_as_uint(f);
  u += 0x7fffu + ((u >> 16) & 1u);
  return (unsigned short)(u >> 16);
}

// 64-lane sum via DPP (row_shr 1,2,4,8 then row_bcast15/31). Result in lane 63.
__device__ __forceinline__ float wave_sum64(float v) {
  v += __int_as_float(__builtin_amdgcn_update_dpp(0, __float_as_int(v), 0x111, 0xf, 0xf, true));
  v += __int_as_float(__builtin_amdgcn_update_dpp(0, __float_as_int(v), 0x112, 0xf, 0xf, true));
  v += __int_as_float(__builtin_amdgcn_update_dpp(0, __float_as_int(v), 0x114, 0xf, 0xf, true));
  v += __int_as_float(__builtin_amdgcn_update_dpp(0, __float_as_int(v), 0x118, 0xf, 0xf, true));
  v += __int_as_float(__builtin_amdgcn_update_dpp(0, __float_as_int(v), 0x142, 0xf, 0xf, true));
  v += __int_as_float(__builtin_amdgcn_update_dpp(0, __float_as_int(v), 0x143, 0xf, 0xf, true));
  return v;
}

// Grid barrier: monotonic counter in d_ws (zeroed per launch by hipMemsetAsync).
__device__ __forceinline__ void gridbar(unsigned* bar, unsigned want) {
  __builtin_amdgcn_fence(__ATOMIC_RELEASE, "agent");
  __syncthreads();
  if (threadIdx.x == 0) {
    __hip_atomic_fetch_add(bar, 1u, __ATOMIC_RELAXED, __HIP_MEMORY_SCOPE_AGENT);
    unsigned v;
    do { v = __hip_atomic_load(bar, __ATOMIC_RELAXED, __HIP_MEMORY_SCOPE_AGENT); } while (v < want);
  }
  __syncthreads();
  __builtin_amdgcn_fence(__ATOMIC_ACQUIRE, "agent");
}

// ---------------- pre-projection: XG[m, 0:1536] = emb[x[m]] @ {Wr,Wz,Wh}[:, :512]^T + bias ----
__global__ __launch_bounds__(256) void proj_kernel(
    const int* __restrict__ x, const float* __restrict__ emb,
    const float* __restrict__ Wr, const float* __restrict__ Br,
    const float* __restrict__ Wz, const float* __restrict__ Bz,
    const float* __restrict__ Wh, const float* __restrict__ Bh,
    float* __restrict__ XG)
{
  __shared__ float As[32][68];
  __shared__ float Bs[32][68];
  const int tid = threadIdx.x;
  const int bx = blockIdx.x;   // N tile: 0..23
  const int by = blockIdx.y;   // M tile: 0..127
  const int tx = tid & 15, ty = tid >> 4;
  float acc[4][4] = {{0.f}};

  for (int k0 = 0; k0 < ED; k0 += 32) {
    #pragma unroll
    for (int it = 0; it < 2; ++it) {
      const int s   = tid + it * 256;
      const int row = s >> 3;
      const int c4  = (s & 7) << 2;
      {
        const int m    = by * 64 + row;
        const int vrow = x[m];
        const float4 v = *(const float4*)(emb + (size_t)vrow * ED + k0 + c4);
        As[c4+0][row] = v.x; As[c4+1][row] = v.y; As[c4+2][row] = v.z; As[c4+3][row] = v.w;
      }
      {
        const int j  = bx * 64 + row;
        const int g  = j >> 9, jj = j & 511;
        const float* wrow = (g == 0 ? Wr : (g == 1 ? Wz : Wh)) + (size_t)jj * INW;
        const float4 v = *(const float4*)(wrow + k0 + c4);
        Bs[c4+0][row] = v.x; Bs[c4+1][row] = v.y; Bs[c4+2][row] = v.z; Bs[c4+3][row] = v.w;
      }
    }
    __syncthreads();
    #pragma unroll
    for (int k = 0; k < 32; ++k) {
      const float4 a4 = *(const float4*)&As[k][ty << 2];
      const float4 b4 = *(const float4*)&Bs[k][tx << 2];
      const float av[4] = {a4.x, a4.y, a4.z, a4.w};
      const float bv[4] = {b4.x, b4.y, b4.z, b4.w};
      #pragma unroll
      for (int i = 0; i < 4; ++i)
        #pragma unroll
        for (int j = 0; j < 4; ++j)
          acc[i][j] += av[i] * bv[j];
    }
    __syncthreads();
  }
  #pragma unroll
  for (int j = 0; j < 4; ++j) {
    const int jc = bx * 64 + (tx << 2) + j;
    const int g = jc >> 9, jj = jc & 511;
    const float bias = (g == 0 ? Br : (g == 1 ? Bz : Bh))[jj];
    #pragma unroll
    for (int i = 0; i < 4; ++i) {
      const int m = by * 64 + (ty << 2) + i;
      XG[(size_t)m * NG + jc] = acc[i][j] + bias;
    }
  }
}

// ---------------- transpose XG[8192][1536] -> XG_T[1536][8192] --------------------------------
__global__ __launch_bounds__(256) void xgt_kernel(const float* __restrict__ in,
                                                  float* __restrict__ outp)
{
  __shared__ float tile[64][65];
  const int bx = blockIdx.x;  // 0..23  (col tile)
  const int by = blockIdx.y;  // 0..127 (row tile)
  const int tid = threadIdx.x;
  const int c4 = (tid & 15) * 4, r0 = tid >> 4;
  #pragma unroll
  for (int rr = 0; rr < 4; ++rr) {
    const int r = r0 + rr * 16;
    const float4 v = *(const float4*)(in + (size_t)(by * 64 + r) * NG + bx * 64 + c4);
    tile[c4+0][r] = v.x; tile[c4+1][r] = v.y; tile[c4+2][r] = v.z; tile[c4+3][r] = v.w;
  }
  __syncthreads();
  const int r4 = (tid & 15) * 4, c0 = tid >> 4;
  #pragma unroll
  for (int cc = 0; cc < 4; ++cc) {
    const int c = c0 + cc * 16;
    float4 v;
    v.x = tile[c][r4+0]; v.y = tile[c][r4+1]; v.z = tile[c][r4+2]; v.w = tile[c][r4+3];
    *(float4*)(outp + (size_t)(bx * 64 + c) * 8192 + by * 64 + r4) = v;
  }
}

// ---------------- persistent GRU recurrence -------------------------------------------------
// 256 WGs x 256 thr. Phase A: wave owns col cA=wg*4+wv of [r|z] (1024 waves).
// Phase B: waves 0,1 own col jB=wg*2+wv of h_cand (512 waves). 2 grid barriers/step.
__global__ __launch_bounds__(256) void recur_kernel(
    const float* __restrict__ XG_T,   // [1536][8192]
    const float* __restrict__ Wr, const float* __restrict__ Wz, const float* __restrict__ Wh,
    float* __restrict__ h_T,          // [512][64]
    float* __restrict__ h_B,          // [64][512]
    float* __restrict__ u_B,          // [64][512]  (r*h)
    float* __restrict__ z_T,          // [512][64]
    unsigned short* __restrict__ Habf,// [8192][512] bf16
    float* __restrict__ outT,         // [512][64]  (hT.T)
    unsigned* __restrict__ bar)
{
  const int tid = threadIdx.x, wg = blockIdx.x;
  const int wv = tid >> 6, lane = tid & 63;

  const int cA   = wg * 4 + wv;        // 0..1023
  const int gA   = cA >> 9;            // 0=r, 1=z
  const int colA = cA & 511;
  const float* wap = (gA ? Wz : Wr) + (size_t)colA * INW + ED + lane * 8;
  const float4 wa0 = *(const float4*)wap;
  const float4 wa1 = *(const float4*)(wap + 4);

  const int jB = wg * 2 + wv;          // valid when wv<2
  float4 wb0 = {0,0,0,0}, wb1 = {0,0,0,0};
  if (wv < 2) {
    const float* wbp = Wh + (size_t)jB * INW + ED + lane * 8;
    wb0 = *(const float4*)wbp;
    wb1 = *(const float4*)(wbp + 4);
  }

  unsigned want = 0;
  for (int t = 0; t < SQ; ++t) {
    // ---- phase A: r,z gates ----
    {
      float resf = 0.0f;
      #pragma unroll 4
      for (int b = 0; b < BA; ++b) {
        const float4 p0 = *(const float4*)(h_B + (size_t)b * HD + lane * 8);
        const float4 p1 = *(const float4*)(h_B + (size_t)b * HD + lane * 8 + 4);
        float a = wa0.x*p0.x + wa0.y*p0.y + wa0.z*p0.z + wa0.w*p0.w
                + wa1.x*p1.x + wa1.y*p1.y + wa1.z*p1.z + wa1.w*p1.w;
        a = wave_sum64(a);
        const int s = __builtin_amdgcn_readlane(__float_as_int(a), 63);  // wave-uniform
        resf = (lane == b) ? __int_as_float(s) : resf;
      }
      const float pre = resf + XG_T[(size_t)cA * 8192 + t * BA + lane];
      const float sg = 1.0f / (1.0f + __expf(-pre));
      if (gA == 0) {
        const float hv = h_T[colA * BA + lane];
        u_B[(size_t)lane * HD + colA] = sg * hv;
      } else {
        z_T[colA * BA + lane] = sg;
      }
    }
    want += NWG; gridbar(bar, want);

    // ---- phase B: h_cand + combine ----
    if (wv < 2) {
      float resf = 0.0f;
      #pragma unroll 4
      for (int b = 0; b < BA; ++b) {
        const float4 p0 = *(const float4*)(u_B + (size_t)b * HD + lane * 8);
        const float4 p1 = *(const float4*)(u_B + (size_t)b * HD + lane * 8 + 4);
        float a = wb0.x*p0.x + wb0.y*p0.y + wb0.z*p0.z + wb0.w*p0.w
                + wb1.x*p1.x + wb1.y*p1.y + wb1.z*p1.z + wb1.w*p1.w;
        a = wave_sum64(a);
        const int s = __builtin_amdgcn_readlane(__float_as_int(a), 63);
        resf = (lane == b) ? __int_as_float(s) : resf;
      }
      const float pre = resf + XG_T[(size_t)(1024 + jB) * 8192 + t * BA + lane];
      const float e  = __expf(2.0f * pre);          // tanh, inf-safe
      const float hc = 1.0f - 2.0f / (e + 1.0f);
      const float z  = z_T[jB * BA + lane];
      const float hp = h_T[jB * BA + lane];
      const float hn = z * hp + (1.0f - z) * hc;
      h_T[jB * BA + lane] = hn;
      h_B[(size_t)lane * HD + jB] = hn;
      Habf[(size_t)(t * BA + lane) * HD + jB] = f2bf(hn);
      if (t == SQ - 1) outT[jB * BA + lane] = hn;
    }
    want += NWG; gridbar(bar, want);
  }
}

// ---------------- final output GEMM: Y = Habf @ W^T + b  (bf16 MFMA, fp32 out) ----------------
__global__ __launch_bounds__(256) void out_gemm_kernel(
    const unsigned short* __restrict__ A,  // 8192 x 512 bf16
    const float* __restrict__ Bw,          // 32000 x 512 f32
    const float* __restrict__ bias,        // 32000
    float* __restrict__ Y)                 // 8192 x 32000
{
  __shared__ unsigned short As[128 * 32];
  __shared__ unsigned short Bs[128 * 32];
  const int bid = blockIdx.x;
  const int tn = bid % 250, tm = bid / 250;
  const int tid = threadIdx.x;
  const int wave = tid >> 6, lane = tid & 63;
  const int wm = wave >> 1, wn = wave & 1;
  const int l15 = lane & 15, lhi = lane >> 4;
  f32x4 acc[4][4] = {};

  for (int k0 = 0; k0 < 512; k0 += 32) {
    #pragma unroll
    for (int it = 0; it < 2; ++it) {
      const int ss  = tid + it * 256;
      const int row = ss >> 2;
      const int c8  = (ss & 3) << 3;
      *(uint4*)(As + row * 32 + c8) =
          *(const uint4*)(A + (size_t)(tm * 128 + row) * 512 + k0 + c8);
      const float4 b0 = *(const float4*)(Bw + (size_t)(tn * 128 + row) * 512 + k0 + c8);
      const float4 b1 = *(const float4*)(Bw + (size_t)(tn * 128 + row) * 512 + k0 + c8 + 4);
      union { unsigned short h[8]; uint4 u; } cv;
      cv.h[0] = f2bf(b0.x); cv.h[1] = f2bf(b0.y); cv.h[2] = f2bf(b0.z); cv.h[3] = f2bf(b0.w);
      cv.h[4] = f2bf(b1.x); cv.h[5] = f2bf(b1.y); cv.h[6] = f2bf(b1.z); cv.h[7] = f2bf(b1.w);
      *(uint4*)(Bs + row * 32 + c8) = cv.u;
    }
    __syncthreads();
    sh8 af[4], bfr[4];
    #pragma unroll
    for (int mi = 0; mi < 4; ++mi)
      af[mi] = *(const sh8*)(As + (wm * 64 + mi * 16 + l15) * 32 + lhi * 8);
    #pragma unroll
    for (int ni = 0; ni < 4; ++ni)
      bfr[ni] = *(const sh8*)(Bs + (wn * 64 + ni * 16 + l15) * 32 + lhi * 8);
    #pragma unroll
    for (int mi = 0; mi < 4; ++mi)
      #pragma unroll
      for (int ni = 0; ni < 4; ++ni)
        acc[mi][ni] = __builtin_amdgcn_mfma_f32_16x16x32_bf16(af[mi], bfr[ni], acc[mi][ni], 0, 0, 0);
    __syncthreads();
  }

  #pragma unroll
  for (int ni = 0; ni < 4; ++ni) {
    const int col = tn * 128 + wn * 64 + ni * 16 + l15;
    const float bv = bias[col];
    #pragma unroll
    for (int mi = 0; mi < 4; ++mi) {
      const int row0 = tm * 128 + wm * 64 + mi * 16 + lhi * 4;
      #pragma unroll
      for (int q = 0; q < 4; ++q)
        Y[(size_t)(row0 + q) * VSZ + col] = acc[mi][ni][q] + bv;
    }
  }
}

extern "C" void kernel_launch(void* const* d_in, const int* in_sizes, int n_in,
                              void* d_out, int out_size, void* d_ws, size_t ws_size,
                              hipStream_t stream)
{
  const int*   x   = (const int*)  d_in[0];
  const float* emb = (const float*)d_in[1];
  const float* Wr  = (const float*)d_in[2];
  const float* Br  = (const float*)d_in[3];
  const float* Wz  = (const float*)d_in[4];
  const float* Bz  = (const float*)d_in[5];
  const float* Wh  = (const float*)d_in[6];
  const float* Bh  = (const float*)d_in[7];
  const float* W   = (const float*)d_in[8];
  const float* bo  = (const float*)d_in[9];
  float* out = (float*)d_out;

  char* ws = (char*)d_ws;
  float*          h_T  = (float*)(ws);                    // 128 KiB [512][64]
  float*          h_B  = (float*)(ws + 131072);           // 128 KiB [64][512]
  float*          u_B  = (float*)(ws + 262144);           // 128 KiB [64][512]
  float*          z_T  = (float*)(ws + 393216);           // 128 KiB [512][64]
  unsigned*       bar  = (unsigned*)(ws + 524288);        // 4 KiB barrier counter
  unsigned short* Habf = (unsigned short*)(ws + 528384);  // 8 MiB bf16 h history

  // XG (pre-projection) and XG_T overlay d_out; both dead before out_gemm writes Y.
  float* XG   = out;                  // [8192][1536]
  float* XG_T = out + 12582912;       // [1536][8192]
  float* outT = out + 262144000ll;    // hT.T region

  // zero h_T, h_B, u_B, z_T, barrier counter (deterministic across graph replays)
  (void)hipMemsetAsync(ws, 0, 528384, stream);

  proj_kernel<<<dim3(24, 128), 256, 0, stream>>>(x, emb, Wr, Br, Wz, Bz, Wh, Bh, XG);
  xgt_kernel<<<dim3(24, 128), 256, 0, stream>>>(XG, XG_T);
  recur_kernel<<<NWG, 256, 0, stream>>>(XG_T, Wr, Wz, Wh, h_T, h_B, u_B, z_T, Habf, outT, bar);
  out_gemm_kernel<<<16000, 256, 0, stream>>>(Habf, W, bo, out);
}

// Round 4
// 4405.360 us; speedup vs baseline: 2.8278x; 2.8278x over previous
//
#include <hip/hip_runtime.h>
#include <cstdint>
#include <cstddef>

#define VSZ 32000
#define ED  512
#define HD  512
#define SQ  128
#define BA  64
#define INW 1024
#define NG  1536
#define NWG 64

typedef __attribute__((ext_vector_type(8))) short sh8;
typedef __attribute__((ext_vector_type(4))) float f32x4;
typedef _Float16 half8 __attribute__((ext_vector_type(8)));

__device__ inline unsigned short f2bf(float f) {
  unsigned int u = __float_as_uint(f);
  u += 0x7fffu + ((u >> 16) & 1u);
  return (unsigned short)(u >> 16);
}

// Grid barrier: monotonic counter in d_ws (zeroed per launch by hipMemsetAsync).
__device__ __forceinline__ void gridbar(unsigned* bar, unsigned want) {
  __builtin_amdgcn_fence(__ATOMIC_RELEASE, "agent");
  __syncthreads();
  if (threadIdx.x == 0) {
    __hip_atomic_fetch_add(bar, 1u, __ATOMIC_RELAXED, __HIP_MEMORY_SCOPE_AGENT);
    unsigned v = __hip_atomic_load(bar, __ATOMIC_RELAXED, __HIP_MEMORY_SCOPE_AGENT);
    while (v < want) {
      __builtin_amdgcn_s_sleep(1);
      v = __hip_atomic_load(bar, __ATOMIC_RELAXED, __HIP_MEMORY_SCOPE_AGENT);
    }
  }
  __syncthreads();
  __builtin_amdgcn_fence(__ATOMIC_ACQUIRE, "agent");
}

// ---------------- pre-projection: XG[m, 0:1536] = emb[x[m]] @ {Wr,Wz,Wh}[:, :512]^T + bias ----
__global__ __launch_bounds__(256) void proj_kernel(
    const int* __restrict__ x, const float* __restrict__ emb,
    const float* __restrict__ Wr, const float* __restrict__ Br,
    const float* __restrict__ Wz, const float* __restrict__ Bz,
    const float* __restrict__ Wh, const float* __restrict__ Bh,
    float* __restrict__ XG)
{
  __shared__ float As[32][68];
  __shared__ float Bs[32][68];
  const int tid = threadIdx.x;
  const int bx = blockIdx.x;   // N tile: 0..23
  const int by = blockIdx.y;   // M tile: 0..127
  const int tx = tid & 15, ty = tid >> 4;
  float acc[4][4] = {{0.f}};

  for (int k0 = 0; k0 < ED; k0 += 32) {
    #pragma unroll
    for (int it = 0; it < 2; ++it) {
      const int s   = tid + it * 256;
      const int row = s >> 3;
      const int c4  = (s & 7) << 2;
      {
        const int m    = by * 64 + row;
        const int vrow = x[m];
        const float4 v = *(const float4*)(emb + (size_t)vrow * ED + k0 + c4);
        As[c4+0][row] = v.x; As[c4+1][row] = v.y; As[c4+2][row] = v.z; As[c4+3][row] = v.w;
      }
      {
        const int j  = bx * 64 + row;
        const int g  = j >> 9, jj = j & 511;
        const float* wrow = (g == 0 ? Wr : (g == 1 ? Wz : Wh)) + (size_t)jj * INW;
        const float4 v = *(const float4*)(wrow + k0 + c4);
        Bs[c4+0][row] = v.x; Bs[c4+1][row] = v.y; Bs[c4+2][row] = v.z; Bs[c4+3][row] = v.w;
      }
    }
    __syncthreads();
    #pragma unroll
    for (int k = 0; k < 32; ++k) {
      const float4 a4 = *(const float4*)&As[k][ty << 2];
      const float4 b4 = *(const float4*)&Bs[k][tx << 2];
      const float av[4] = {a4.x, a4.y, a4.z, a4.w};
      const float bv[4] = {b4.x, b4.y, b4.z, b4.w};
      #pragma unroll
      for (int i = 0; i < 4; ++i)
        #pragma unroll
        for (int j = 0; j < 4; ++j)
          acc[i][j] += av[i] * bv[j];
    }
    __syncthreads();
  }
  #pragma unroll
  for (int j = 0; j < 4; ++j) {
    const int jc = bx * 64 + (tx << 2) + j;
    const int g = jc >> 9, jj = jc & 511;
    const float bias = (g == 0 ? Br : (g == 1 ? Bz : Bh))[jj];
    #pragma unroll
    for (int i = 0; i < 4; ++i) {
      const int m = by * 64 + (ty << 2) + i;
      XG[(size_t)m * NG + jc] = acc[i][j] + bias;
    }
  }
}

// ---------------- persistent GRU recurrence (MFMA, weights in VGPRs, no LDS) ------------------
// 64 WGs x 256 thr (4 waves). Phase A: WG owns 16 cols of [r|z] (wg<32: r, wg>=32: z).
// Phase B: WGs 0..31 own 16 cols of h_cand. Each wave = one 16-row m-tile of the 64 batches.
// A-operand (h / u) read directly from global fp16 buffers as MFMA fragments.
__global__ __launch_bounds__(256) void recur_kernel(
    const float* __restrict__ XG,     // [8192][1536]
    const float* __restrict__ Wr, const float* __restrict__ Wz, const float* __restrict__ Wh,
    float* __restrict__ h32,          // [64][512] fp32
    float* __restrict__ z32,          // [64][512] fp32
    _Float16* __restrict__ hF,        // [64][512] fp16
    _Float16* __restrict__ uF,        // [64][512] fp16 (r*h)
    unsigned short* __restrict__ Habf,// [8192][512] bf16
    float* __restrict__ outT,         // [512][64]  (hT.T)
    unsigned* __restrict__ bar)
{
  const int tid = threadIdx.x, wg = blockIdx.x;
  const int wv = tid >> 6, lane = tid & 63;
  const int l15 = lane & 15, lhi = lane >> 4;
  const int mrow = wv * 16 + l15;          // A-fragment row (batch)
  const int gA   = wg >> 5;                // 0: r-cols, 1: z-cols
  const int cA   = wg * 16 + l15;          // 0..1023 (phase-A column)
  const int colA = cA & 511;
  const int jB   = (wg & 31) * 16 + l15;   // phase-B column (valid when wg<32)

  // ---- load weight B-fragments into registers (fp16), once ----
  half8 wfA[16], wfB[16];
  {
    const float* WA = (gA ? Wz : Wr) + (size_t)colA * INW + ED + lhi * 8;
    #pragma unroll
    for (int s = 0; s < 16; ++s) {
      const float4 a = *(const float4*)(WA + s * 32);
      const float4 b = *(const float4*)(WA + s * 32 + 4);
      half8 w;
      w[0]=(_Float16)a.x; w[1]=(_Float16)a.y; w[2]=(_Float16)a.z; w[3]=(_Float16)a.w;
      w[4]=(_Float16)b.x; w[5]=(_Float16)b.y; w[6]=(_Float16)b.z; w[7]=(_Float16)b.w;
      wfA[s] = w;
    }
    const float* WB = Wh + (size_t)jB * INW + ED + lhi * 8;
    #pragma unroll
    for (int s = 0; s < 16; ++s) {
      const float4 a = *(const float4*)(WB + s * 32);
      const float4 b = *(const float4*)(WB + s * 32 + 4);
      half8 w;
      w[0]=(_Float16)a.x; w[1]=(_Float16)a.y; w[2]=(_Float16)a.z; w[3]=(_Float16)a.w;
      w[4]=(_Float16)b.x; w[5]=(_Float16)b.y; w[6]=(_Float16)b.z; w[7]=(_Float16)b.w;
      wfB[s] = w;
    }
  }

  unsigned want = 0;
  for (int t = 0; t < SQ; ++t) {
    // ---- phase A: pre = h @ W{r,z}h^T ; epilogue sigmoid -> uF / z32 ----
    {
      f32x4 acc = {};
      #pragma unroll
      for (int s = 0; s < 16; ++s) {
        const half8 hf = *(const half8*)(hF + (size_t)mrow * HD + s * 32 + lhi * 8);
        acc = __builtin_amdgcn_mfma_f32_16x16x32_f16(hf, wfA[s], acc, 0, 0, 0);
      }
      #pragma unroll
      for (int q = 0; q < 4; ++q) {
        const int b = wv * 16 + lhi * 4 + q;
        const float pre = acc[q] + XG[(size_t)(t * BA + b) * NG + cA];
        const float sg = 1.0f / (1.0f + __expf(-pre));
        if (gA == 0) {
          uF[(size_t)b * HD + colA] = (_Float16)(sg * h32[(size_t)b * HD + colA]);
        } else {
          z32[(size_t)b * HD + colA] = sg;
        }
      }
    }
    want += NWG; gridbar(bar, want);

    // ---- phase B: pre = u @ Whh^T ; epilogue tanh + combine ----
    if (wg < 32) {
      f32x4 acc = {};
      #pragma unroll
      for (int s = 0; s < 16; ++s) {
        const half8 uf = *(const half8*)(uF + (size_t)mrow * HD + s * 32 + lhi * 8);
        acc = __builtin_amdgcn_mfma_f32_16x16x32_f16(uf, wfB[s], acc, 0, 0, 0);
      }
      #pragma unroll
      for (int q = 0; q < 4; ++q) {
        const int b = wv * 16 + lhi * 4 + q;
        const float pre = acc[q] + XG[(size_t)(t * BA + b) * NG + 1024 + jB];
        const float e  = __expf(2.0f * pre);          // tanh, inf-safe
        const float hc = 1.0f - 2.0f / (e + 1.0f);
        const float z  = z32[(size_t)b * HD + jB];
        const float ho = h32[(size_t)b * HD + jB];
        const float hn = z * ho + (1.0f - z) * hc;
        h32[(size_t)b * HD + jB] = hn;
        hF[(size_t)b * HD + jB]  = (_Float16)hn;
        Habf[(size_t)(t * BA + b) * HD + jB] = f2bf(hn);
        if (t == SQ - 1) outT[jB * BA + b] = hn;
      }
    }
    want += NWG; gridbar(bar, want);
  }
}

// ---------------- final output GEMM: Y = Habf @ W^T + b  (bf16 MFMA, fp32 out) ----------------
__global__ __launch_bounds__(256) void out_gemm_kernel(
    const unsigned short* __restrict__ A,  // 8192 x 512 bf16
    const float* __restrict__ Bw,          // 32000 x 512 f32
    const float* __restrict__ bias,        // 32000
    float* __restrict__ Y)                 // 8192 x 32000
{
  __shared__ unsigned short As[128 * 32];
  __shared__ unsigned short Bs[128 * 32];
  const int bid = blockIdx.x;
  const int tn = bid % 250, tm = bid / 250;
  const int tid = threadIdx.x;
  const int wave = tid >> 6, lane = tid & 63;
  const int wm = wave >> 1, wn = wave & 1;
  const int l15 = lane & 15, lhi = lane >> 4;
  f32x4 acc[4][4] = {};

  for (int k0 = 0; k0 < 512; k0 += 32) {
    #pragma unroll
    for (int it = 0; it < 2; ++it) {
      const int ss  = tid + it * 256;
      const int row = ss >> 2;
      const int c8  = (ss & 3) << 3;
      *(uint4*)(As + row * 32 + c8) =
          *(const uint4*)(A + (size_t)(tm * 128 + row) * 512 + k0 + c8);
      const float4 b0 = *(const float4*)(Bw + (size_t)(tn * 128 + row) * 512 + k0 + c8);
      const float4 b1 = *(const float4*)(Bw + (size_t)(tn * 128 + row) * 512 + k0 + c8 + 4);
      union { unsigned short h[8]; uint4 u; } cv;
      cv.h[0] = f2bf(b0.x); cv.h[1] = f2bf(b0.y); cv.h[2] = f2bf(b0.z); cv.h[3] = f2bf(b0.w);
      cv.h[4] = f2bf(b1.x); cv.h[5] = f2bf(b1.y); cv.h[6] = f2bf(b1.z); cv.h[7] = f2bf(b1.w);
      *(uint4*)(Bs + row * 32 + c8) = cv.u;
    }
    __syncthreads();
    sh8 af[4], bfr[4];
    #pragma unroll
    for (int mi = 0; mi < 4; ++mi)
      af[mi] = *(const sh8*)(As + (wm * 64 + mi * 16 + l15) * 32 + lhi * 8);
    #pragma unroll
    for (int ni = 0; ni < 4; ++ni)
      bfr[ni] = *(const sh8*)(Bs + (wn * 64 + ni * 16 + l15) * 32 + lhi * 8);
    #pragma unroll
    for (int mi = 0; mi < 4; ++mi)
      #pragma unroll
      for (int ni = 0; ni < 4; ++ni)
        acc[mi][ni] = __builtin_amdgcn_mfma_f32_16x16x32_bf16(af[mi], bfr[ni], acc[mi][ni], 0, 0, 0);
    __syncthreads();
  }

  #pragma unroll
  for (int ni = 0; ni < 4; ++ni) {
    const int col = tn * 128 + wn * 64 + ni * 16 + l15;
    const float bv = bias[col];
    #pragma unroll
    for (int mi = 0; mi < 4; ++mi) {
      const int row0 = tm * 128 + wm * 64 + mi * 16 + lhi * 4;
      #pragma unroll
      for (int q = 0; q < 4; ++q)
        Y[(size_t)(row0 + q) * VSZ + col] = acc[mi][ni][q] + bv;
    }
  }
}

extern "C" void kernel_launch(void* const* d_in, const int* in_sizes, int n_in,
                              void* d_out, int out_size, void* d_ws, size_t ws_size,
                              hipStream_t stream)
{
  const int*   x   = (const int*)  d_in[0];
  const float* emb = (const float*)d_in[1];
  const float* Wr  = (const float*)d_in[2];
  const float* Br  = (const float*)d_in[3];
  const float* Wz  = (const float*)d_in[4];
  const float* Bz  = (const float*)d_in[5];
  const float* Wh  = (const float*)d_in[6];
  const float* Bh  = (const float*)d_in[7];
  const float* W   = (const float*)d_in[8];
  const float* bo  = (const float*)d_in[9];
  float* out = (float*)d_out;

  char* ws = (char*)d_ws;
  float*          h32  = (float*)(ws);                    // 128 KiB [64][512]
  float*          z32  = (float*)(ws + 131072);           // 128 KiB [64][512]
  _Float16*       hF   = (_Float16*)(ws + 262144);        //  64 KiB [64][512]
  _Float16*       uF   = (_Float16*)(ws + 327680);        //  64 KiB [64][512]
  unsigned*       bar  = (unsigned*)(ws + 393216);        //   4 KiB barrier counter
  unsigned short* Habf = (unsigned short*)(ws + 397312);  //   8 MiB bf16 h history

  // XG (pre-projection) overlays d_out; dead before out_gemm writes Y.
  float* XG   = out;                  // [8192][1536]
  float* outT = out + 262144000ll;    // hT.T region

  // zero h32, z32, hF, uF, barrier counter (deterministic across graph replays)
  (void)hipMemsetAsync(ws, 0, 397312 + 4096, stream);

  proj_kernel<<<dim3(24, 128), 256, 0, stream>>>(x, emb, Wr, Br, Wz, Bz, Wh, Bh, XG);
  recur_kernel<<<NWG, 256, 0, stream>>>(XG, Wr, Wz, Wh, h32, z32, hF, uF, Habf, outT, bar);
  out_gemm_kernel<<<16000, 256, 0, stream>>>(Habf, W, bo, out);
}

// Round 5
// 3173.336 us; speedup vs baseline: 3.9257x; 1.3882x over previous
//
#include <hip/hip_runtime.h>
#include <cstdint>
#include <cstddef>

#define VSZ 32000
#define ED  512
#define HD  512
#define SQ  128
#define BA  64
#define INW 1024
#define NG  1536
#define NWG 32

typedef __attribute__((ext_vector_type(8))) short sh8;
typedef __attribute__((ext_vector_type(4))) float f32x4;
typedef _Float16 half8 __attribute__((ext_vector_type(8)));

__device__ inline unsigned short f2bf(float f) {
  unsigned int u = __float_as_uint(f);
  u += 0x7fffu + ((u >> 16) & 1u);
  return (unsigned short)(u >> 16);
}

// 16B coherent (agent-scope, sc1) load of a half8 fragment via two 8B relaxed atomics.
__device__ __forceinline__ half8 ldg_agent16(const _Float16* p) {
  unsigned long long lo = __hip_atomic_load((const unsigned long long*)p,
                                            __ATOMIC_RELAXED, __HIP_MEMORY_SCOPE_AGENT);
  unsigned long long hi = __hip_atomic_load((const unsigned long long*)p + 1,
                                            __ATOMIC_RELAXED, __HIP_MEMORY_SCOPE_AGENT);
  union { unsigned long long q[2]; half8 h; } u;
  u.q[0] = lo; u.q[1] = hi;
  return u.h;
}

// Fence-free grid barrier. __syncthreads' implicit s_waitcnt vmcnt(0) drains each wave's
// sc1 stores to the coherence point before tid0 signals; no buffer_wbl2/buffer_inv.
__device__ __forceinline__ void gridbar(unsigned* bar, unsigned want) {
  asm volatile("s_waitcnt vmcnt(0)" ::: "memory");
  __syncthreads();
  if (threadIdx.x == 0) {
    __hip_atomic_fetch_add(bar, 1u, __ATOMIC_RELAXED, __HIP_MEMORY_SCOPE_AGENT);
    unsigned v = __hip_atomic_load(bar, __ATOMIC_RELAXED, __HIP_MEMORY_SCOPE_AGENT);
    while (v < want) {
      __builtin_amdgcn_s_sleep(2);
      v = __hip_atomic_load(bar, __ATOMIC_RELAXED, __HIP_MEMORY_SCOPE_AGENT);
    }
  }
  __syncthreads();
}

// ---------------- pre-projection: XG[m, 0:1536] = emb[x[m]] @ {Wr,Wz,Wh}[:, :512]^T + bias ----
__global__ __launch_bounds__(256) void proj_kernel(
    const int* __restrict__ x, const float* __restrict__ emb,
    const float* __restrict__ Wr, const float* __restrict__ Br,
    const float* __restrict__ Wz, const float* __restrict__ Bz,
    const float* __restrict__ Wh, const float* __restrict__ Bh,
    float* __restrict__ XG)
{
  __shared__ float As[32][68];
  __shared__ float Bs[32][68];
  const int tid = threadIdx.x;
  const int bx = blockIdx.x;   // N tile: 0..23
  const int by = blockIdx.y;   // M tile: 0..127
  const int tx = tid & 15, ty = tid >> 4;
  float acc[4][4] = {{0.f}};

  for (int k0 = 0; k0 < ED; k0 += 32) {
    #pragma unroll
    for (int it = 0; it < 2; ++it) {
      const int s   = tid + it * 256;
      const int row = s >> 3;
      const int c4  = (s & 7) << 2;
      {
        const int m    = by * 64 + row;
        const int vrow = x[m];
        const float4 v = *(const float4*)(emb + (size_t)vrow * ED + k0 + c4);
        As[c4+0][row] = v.x; As[c4+1][row] = v.y; As[c4+2][row] = v.z; As[c4+3][row] = v.w;
      }
      {
        const int j  = bx * 64 + row;
        const int g  = j >> 9, jj = j & 511;
        const float* wrow = (g == 0 ? Wr : (g == 1 ? Wz : Wh)) + (size_t)jj * INW;
        const float4 v = *(const float4*)(wrow + k0 + c4);
        Bs[c4+0][row] = v.x; Bs[c4+1][row] = v.y; Bs[c4+2][row] = v.z; Bs[c4+3][row] = v.w;
      }
    }
    __syncthreads();
    #pragma unroll
    for (int k = 0; k < 32; ++k) {
      const float4 a4 = *(const float4*)&As[k][ty << 2];
      const float4 b4 = *(const float4*)&Bs[k][tx << 2];
      const float av[4] = {a4.x, a4.y, a4.z, a4.w};
      const float bv[4] = {b4.x, b4.y, b4.z, b4.w};
      #pragma unroll
      for (int i = 0; i < 4; ++i)
        #pragma unroll
        for (int j = 0; j < 4; ++j)
          acc[i][j] += av[i] * bv[j];
    }
    __syncthreads();
  }
  #pragma unroll
  for (int j = 0; j < 4; ++j) {
    const int jc = bx * 64 + (tx << 2) + j;
    const int g = jc >> 9, jj = jc & 511;
    const float bias = (g == 0 ? Br : (g == 1 ? Bz : Bh))[jj];
    #pragma unroll
    for (int i = 0; i < 4; ++i) {
      const int m = by * 64 + (ty << 2) + i;
      XG[(size_t)m * NG + jc] = acc[i][j] + bias;
    }
  }
}

// ---------------- persistent GRU recurrence (MFMA, weights in VGPRs, fence-free sync) ---------
// 32 WGs x 256 thr (4 waves). WG w owns columns w*16..w*16+15 of r, z AND h_cand.
// Cross-WG traffic (hF/uF broadcasts) uses agent-scope (sc1) atomics; h32/z32 are WG-private.
__global__ __launch_bounds__(256) void recur_kernel(
    const float* __restrict__ XG,     // [8192][1536]
    const float* __restrict__ Wr, const float* __restrict__ Wz, const float* __restrict__ Wh,
    float* __restrict__ h32,          // [64][512] fp32   (WG-private cols)
    float* __restrict__ z32,          // [64][512] fp32   (WG-private cols)
    _Float16* __restrict__ hF,        // [64][512] fp16   (agent-coherent)
    _Float16* __restrict__ uF,        // [64][512] fp16   (agent-coherent, r*h)
    unsigned short* __restrict__ Habf,// [8192][512] bf16
    float* __restrict__ outT,         // [512][64]  (hT.T)
    unsigned* __restrict__ bar)
{
  const int tid = threadIdx.x, wg = blockIdx.x;
  const int wv = tid >> 6, lane = tid & 63;
  const int l15 = lane & 15, lhi = lane >> 4;
  const int mrow = wv * 16 + l15;          // A-fragment row (batch)
  const int col  = wg * 16 + l15;          // owned column (same for r, z, h_cand)

  // ---- load weight B-fragments into registers (fp16), once ----
  half8 wfR[16], wfZ[16], wfH[16];
  {
    const float* WR = Wr + (size_t)col * INW + ED + lhi * 8;
    const float* WZ = Wz + (size_t)col * INW + ED + lhi * 8;
    const float* WH = Wh + (size_t)col * INW + ED + lhi * 8;
    #pragma unroll
    for (int s = 0; s < 16; ++s) {
      float4 a, b; half8 w;
      a = *(const float4*)(WR + s * 32); b = *(const float4*)(WR + s * 32 + 4);
      w[0]=(_Float16)a.x; w[1]=(_Float16)a.y; w[2]=(_Float16)a.z; w[3]=(_Float16)a.w;
      w[4]=(_Float16)b.x; w[5]=(_Float16)b.y; w[6]=(_Float16)b.z; w[7]=(_Float16)b.w;
      wfR[s] = w;
      a = *(const float4*)(WZ + s * 32); b = *(const float4*)(WZ + s * 32 + 4);
      w[0]=(_Float16)a.x; w[1]=(_Float16)a.y; w[2]=(_Float16)a.z; w[3]=(_Float16)a.w;
      w[4]=(_Float16)b.x; w[5]=(_Float16)b.y; w[6]=(_Float16)b.z; w[7]=(_Float16)b.w;
      wfZ[s] = w;
      a = *(const float4*)(WH + s * 32); b = *(const float4*)(WH + s * 32 + 4);
      w[0]=(_Float16)a.x; w[1]=(_Float16)a.y; w[2]=(_Float16)a.z; w[3]=(_Float16)a.w;
      w[4]=(_Float16)b.x; w[5]=(_Float16)b.y; w[6]=(_Float16)b.z; w[7]=(_Float16)b.w;
      wfH[s] = w;
    }
  }

  unsigned want = 0;
  for (int t = 0; t < SQ; ++t) {
    // ---- phase A: preR/preZ = h @ W{r,z}h^T ; sigmoid -> uF (agent), z32 (private) ----
    {
      half8 ha[16];
      #pragma unroll
      for (int s = 0; s < 16; ++s)
        ha[s] = ldg_agent16(hF + (size_t)mrow * HD + s * 32 + lhi * 8);
      f32x4 accR = {}, accZ = {};
      #pragma unroll
      for (int s = 0; s < 16; ++s) {
        accR = __builtin_amdgcn_mfma_f32_16x16x32_f16(ha[s], wfR[s], accR, 0, 0, 0);
        accZ = __builtin_amdgcn_mfma_f32_16x16x32_f16(ha[s], wfZ[s], accZ, 0, 0, 0);
      }
      #pragma unroll
      for (int q = 0; q < 4; ++q) {
        const int b = wv * 16 + lhi * 4 + q;
        const float preR = accR[q] + XG[(size_t)(t * BA + b) * NG + col];
        const float r  = 1.0f / (1.0f + __expf(-preR));
        const float uv = r * h32[(size_t)b * HD + col];
        const _Float16 uh = (_Float16)uv;
        const unsigned short ub = __builtin_bit_cast(unsigned short, uh);
        const unsigned short ob = (unsigned short)__shfl_xor((int)ub, 1);
        if (!(l15 & 1)) {
          const unsigned wrd = (unsigned)ub | ((unsigned)ob << 16);
          __hip_atomic_store((unsigned*)(uF + (size_t)b * HD + col), wrd,
                             __ATOMIC_RELAXED, __HIP_MEMORY_SCOPE_AGENT);
        }
        const float preZ = accZ[q] + XG[(size_t)(t * BA + b) * NG + 512 + col];
        z32[(size_t)b * HD + col] = 1.0f / (1.0f + __expf(-preZ));
      }
    }
    want += NWG; gridbar(bar, want);

    // ---- phase B: pre = u @ Whh^T ; tanh + combine -> h32 (private), hF (agent) ----
    {
      half8 ua[16];
      #pragma unroll
      for (int s = 0; s < 16; ++s)
        ua[s] = ldg_agent16(uF + (size_t)mrow * HD + s * 32 + lhi * 8);
      f32x4 acc = {};
      #pragma unroll
      for (int s = 0; s < 16; ++s)
        acc = __builtin_amdgcn_mfma_f32_16x16x32_f16(ua[s], wfH[s], acc, 0, 0, 0);
      #pragma unroll
      for (int q = 0; q < 4; ++q) {
        const int b = wv * 16 + lhi * 4 + q;
        const float pre = acc[q] + XG[(size_t)(t * BA + b) * NG + 1024 + col];
        const float e  = __expf(2.0f * pre);          // tanh, inf-safe
        const float hc = 1.0f - 2.0f / (e + 1.0f);
        const float z  = z32[(size_t)b * HD + col];
        const float ho = h32[(size_t)b * HD + col];
        const float hn = z * ho + (1.0f - z) * hc;
        h32[(size_t)b * HD + col] = hn;
        Habf[(size_t)(t * BA + b) * HD + col] = f2bf(hn);
        const _Float16 hh = (_Float16)hn;
        const unsigned short hb = __builtin_bit_cast(unsigned short, hh);
        const unsigned short hob = (unsigned short)__shfl_xor((int)hb, 1);
        if (!(l15 & 1)) {
          const unsigned wrd = (unsigned)hb | ((unsigned)hob << 16);
          __hip_atomic_store((unsigned*)(hF + (size_t)b * HD + col), wrd,
                             __ATOMIC_RELAXED, __HIP_MEMORY_SCOPE_AGENT);
        }
        if (t == SQ - 1) outT[col * BA + b] = hn;
      }
    }
    want += NWG; gridbar(bar, want);
  }
}

// ---------------- final output GEMM: Y = Habf @ W^T + b  (bf16 MFMA, fp32 out) ----------------
__global__ __launch_bounds__(256) void out_gemm_kernel(
    const unsigned short* __restrict__ A,  // 8192 x 512 bf16
    const float* __restrict__ Bw,          // 32000 x 512 f32
    const float* __restrict__ bias,        // 32000
    float* __restrict__ Y)                 // 8192 x 32000
{
  __shared__ unsigned short As[128 * 32];
  __shared__ unsigned short Bs[128 * 32];
  const int bid = blockIdx.x;
  const int tn = bid % 250, tm = bid / 250;
  const int tid = threadIdx.x;
  const int wave = tid >> 6, lane = tid & 63;
  const int wm = wave >> 1, wn = wave & 1;
  const int l15 = lane & 15, lhi = lane >> 4;
  f32x4 acc[4][4] = {};

  for (int k0 = 0; k0 < 512; k0 += 32) {
    #pragma unroll
    for (int it = 0; it < 2; ++it) {
      const int ss  = tid + it * 256;
      const int row = ss >> 2;
      const int c8  = (ss & 3) << 3;
      *(uint4*)(As + row * 32 + c8) =
          *(const uint4*)(A + (size_t)(tm * 128 + row) * 512 + k0 + c8);
      const float4 b0 = *(const float4*)(Bw + (size_t)(tn * 128 + row) * 512 + k0 + c8);
      const float4 b1 = *(const float4*)(Bw + (size_t)(tn * 128 + row) * 512 + k0 + c8 + 4);
      union { unsigned short h[8]; uint4 u; } cv;
      cv.h[0] = f2bf(b0.x); cv.h[1] = f2bf(b0.y); cv.h[2] = f2bf(b0.z); cv.h[3] = f2bf(b0.w);
      cv.h[4] = f2bf(b1.x); cv.h[5] = f2bf(b1.y); cv.h[6] = f2bf(b1.z); cv.h[7] = f2bf(b1.w);
      *(uint4*)(Bs + row * 32 + c8) = cv.u;
    }
    __syncthreads();
    sh8 af[4], bfr[4];
    #pragma unroll
    for (int mi = 0; mi < 4; ++mi)
      af[mi] = *(const sh8*)(As + (wm * 64 + mi * 16 + l15) * 32 + lhi * 8);
    #pragma unroll
    for (int ni = 0; ni < 4; ++ni)
      bfr[ni] = *(const sh8*)(Bs + (wn * 64 + ni * 16 + l15) * 32 + lhi * 8);
    #pragma unroll
    for (int mi = 0; mi < 4; ++mi)
      #pragma unroll
      for (int ni = 0; ni < 4; ++ni)
        acc[mi][ni] = __builtin_amdgcn_mfma_f32_16x16x32_bf16(af[mi], bfr[ni], acc[mi][ni], 0, 0, 0);
    __syncthreads();
  }

  #pragma unroll
  for (int ni = 0; ni < 4; ++ni) {
    const int col = tn * 128 + wn * 64 + ni * 16 + l15;
    const float bv = bias[col];
    #pragma unroll
    for (int mi = 0; mi < 4; ++mi) {
      const int row0 = tm * 128 + wm * 64 + mi * 16 + lhi * 4;
      #pragma unroll
      for (int q = 0; q < 4; ++q)
        Y[(size_t)(row0 + q) * VSZ + col] = acc[mi][ni][q] + bv;
    }
  }
}

extern "C" void kernel_launch(void* const* d_in, const int* in_sizes, int n_in,
                              void* d_out, int out_size, void* d_ws, size_t ws_size,
                              hipStream_t stream)
{
  const int*   x   = (const int*)  d_in[0];
  const float* emb = (const float*)d_in[1];
  const float* Wr  = (const float*)d_in[2];
  const float* Br  = (const float*)d_in[3];
  const float* Wz  = (const float*)d_in[4];
  const float* Bz  = (const float*)d_in[5];
  const float* Wh  = (const float*)d_in[6];
  const float* Bh  = (const float*)d_in[7];
  const float* W   = (const float*)d_in[8];
  const float* bo  = (const float*)d_in[9];
  float* out = (float*)d_out;

  char* ws = (char*)d_ws;
  float*          h32  = (float*)(ws);                    // 128 KiB [64][512]
  float*          z32  = (float*)(ws + 131072);           // 128 KiB [64][512]
  _Float16*       hF   = (_Float16*)(ws + 262144);        //  64 KiB [64][512]
  _Float16*       uF   = (_Float16*)(ws + 327680);        //  64 KiB [64][512]
  unsigned*       bar  = (unsigned*)(ws + 393216);        //   4 KiB barrier counter
  unsigned short* Habf = (unsigned short*)(ws + 397312);  //   8 MiB bf16 h history

  // XG (pre-projection) overlays d_out; dead before out_gemm writes Y.
  float* XG   = out;                  // [8192][1536]
  float* outT = out + 262144000ll;    // hT.T region

  // zero h32, z32, hF, uF, barrier counter (deterministic across graph replays)
  (void)hipMemsetAsync(ws, 0, 397312 + 4096, stream);

  proj_kernel<<<dim3(24, 128), 256, 0, stream>>>(x, emb, Wr, Br, Wz, Bz, Wh, Bh, XG);
  recur_kernel<<<NWG, 256, 0, stream>>>(XG, Wr, Wz, Wh, h32, z32, hF, uF, Habf, outT, bar);
  out_gemm_kernel<<<16000, 256, 0, stream>>>(Habf, W, bo, out);
}

// Round 6
// 2847.817 us; speedup vs baseline: 4.3744x; 1.1143x over previous
//
#include <hip/hip_runtime.h>
#include <cstdint>
#include <cstddef>

#define VSZ 32000
#define ED  512
#define HD  512
#define SQ  128
#define BA  64
#define INW 1024
#define NG  1536
#define NWG 32

typedef __attribute__((ext_vector_type(8))) short sh8;
typedef __attribute__((ext_vector_type(4))) float f32x4;
typedef _Float16 half8 __attribute__((ext_vector_type(8)));

__device__ inline unsigned short f2bf(float f) {
  unsigned int u = __float_as_uint(f);
  u += 0x7fffu + ((u >> 16) & 1u);
  return (unsigned short)(u >> 16);
}

// 16B coherent (agent-scope, sc1) load of a half8 fragment via two 8B relaxed atomics.
__device__ __forceinline__ half8 ldg_agent16(const _Float16* p) {
  unsigned long long lo = __hip_atomic_load((const unsigned long long*)p,
                                            __ATOMIC_RELAXED, __HIP_MEMORY_SCOPE_AGENT);
  unsigned long long hi = __hip_atomic_load((const unsigned long long*)p + 1,
                                            __ATOMIC_RELAXED, __HIP_MEMORY_SCOPE_AGENT);
  union { unsigned long long q[2]; half8 h; } u;
  u.q[0] = lo; u.q[1] = hi;
  return u.h;
}

// Contention-free grid barrier: per-WG flag stores (parallel, no RMW) + all-lane poll.
// vmcnt(0)+__syncthreads drains this wave's sc1 data stores before the flag store.
__device__ __forceinline__ void gridbar(unsigned* flags, unsigned epoch, int wg) {
  asm volatile("s_waitcnt vmcnt(0)" ::: "memory");
  __syncthreads();
  if (threadIdx.x < 64) {
    const int lane = threadIdx.x;
    if (lane == 0)
      __hip_atomic_store(flags + wg, epoch, __ATOMIC_RELAXED, __HIP_MEMORY_SCOPE_AGENT);
    unsigned v = __hip_atomic_load(flags + (lane & (NWG - 1)),
                                   __ATOMIC_RELAXED, __HIP_MEMORY_SCOPE_AGENT);
    while (!__all((int)(v >= epoch))) {
      __builtin_amdgcn_s_sleep(1);
      v = __hip_atomic_load(flags + (lane & (NWG - 1)),
                            __ATOMIC_RELAXED, __HIP_MEMORY_SCOPE_AGENT);
    }
  }
  __syncthreads();
}

// ---------------- pre-projection: XG[m, 0:1536] = emb[x[m]] @ {Wr,Wz,Wh}[:, :512]^T + bias ----
__global__ __launch_bounds__(256) void proj_kernel(
    const int* __restrict__ x, const float* __restrict__ emb,
    const float* __restrict__ Wr, const float* __restrict__ Br,
    const float* __restrict__ Wz, const float* __restrict__ Bz,
    const float* __restrict__ Wh, const float* __restrict__ Bh,
    float* __restrict__ XG)
{
  __shared__ float As[32][68];
  __shared__ float Bs[32][68];
  const int tid = threadIdx.x;
  const int bx = blockIdx.x;   // N tile: 0..23
  const int by = blockIdx.y;   // M tile: 0..127
  const int tx = tid & 15, ty = tid >> 4;
  float acc[4][4] = {{0.f}};

  for (int k0 = 0; k0 < ED; k0 += 32) {
    #pragma unroll
    for (int it = 0; it < 2; ++it) {
      const int s   = tid + it * 256;
      const int row = s >> 3;
      const int c4  = (s & 7) << 2;
      {
        const int m    = by * 64 + row;
        const int vrow = x[m];
        const float4 v = *(const float4*)(emb + (size_t)vrow * ED + k0 + c4);
        As[c4+0][row] = v.x; As[c4+1][row] = v.y; As[c4+2][row] = v.z; As[c4+3][row] = v.w;
      }
      {
        const int j  = bx * 64 + row;
        const int g  = j >> 9, jj = j & 511;
        const float* wrow = (g == 0 ? Wr : (g == 1 ? Wz : Wh)) + (size_t)jj * INW;
        const float4 v = *(const float4*)(wrow + k0 + c4);
        Bs[c4+0][row] = v.x; Bs[c4+1][row] = v.y; Bs[c4+2][row] = v.z; Bs[c4+3][row] = v.w;
      }
    }
    __syncthreads();
    #pragma unroll
    for (int k = 0; k < 32; ++k) {
      const float4 a4 = *(const float4*)&As[k][ty << 2];
      const float4 b4 = *(const float4*)&Bs[k][tx << 2];
      const float av[4] = {a4.x, a4.y, a4.z, a4.w};
      const float bv[4] = {b4.x, b4.y, b4.z, b4.w};
      #pragma unroll
      for (int i = 0; i < 4; ++i)
        #pragma unroll
        for (int j = 0; j < 4; ++j)
          acc[i][j] += av[i] * bv[j];
    }
    __syncthreads();
  }
  #pragma unroll
  for (int j = 0; j < 4; ++j) {
    const int jc = bx * 64 + (tx << 2) + j;
    const int g = jc >> 9, jj = jc & 511;
    const float bias = (g == 0 ? Br : (g == 1 ? Bz : Bh))[jj];
    #pragma unroll
    for (int i = 0; i < 4; ++i) {
      const int m = by * 64 + (ty << 2) + i;
      XG[(size_t)m * NG + jc] = acc[i][j] + bias;
    }
  }
}

// ---------------- persistent GRU recurrence (MFMA, weights in VGPRs, flag barrier) -----------
// 32 WGs x 256 thr (4 waves). WG w owns columns w*16..w*16+15 of r, z AND h_cand.
// Cross-WG traffic (hF/uF broadcasts) uses agent-scope (sc1) atomics; h32/z32 are WG-private.
__global__ __launch_bounds__(256) void recur_kernel(
    const float* __restrict__ XG,     // [8192][1536]
    const float* __restrict__ Wr, const float* __restrict__ Wz, const float* __restrict__ Wh,
    float* __restrict__ h32,          // [64][512] fp32   (WG-private cols)
    float* __restrict__ z32,          // [64][512] fp32   (WG-private cols)
    _Float16* __restrict__ hF,        // [64][512] fp16   (agent-coherent)
    _Float16* __restrict__ uF,        // [64][512] fp16   (agent-coherent, r*h)
    unsigned short* __restrict__ Habf,// [8192][512] bf16
    float* __restrict__ outT,         // [512][64]  (hT.T)
    unsigned* __restrict__ flags)
{
  const int tid = threadIdx.x, wg = blockIdx.x;
  const int wv = tid >> 6, lane = tid & 63;
  const int l15 = lane & 15, lhi = lane >> 4;
  const int mrow = wv * 16 + l15;          // A-fragment row (batch)
  const int col  = wg * 16 + l15;          // owned column (same for r, z, h_cand)

  // ---- load weight B-fragments into registers (fp16), once ----
  half8 wfR[16], wfZ[16], wfH[16];
  {
    const float* WR = Wr + (size_t)col * INW + ED + lhi * 8;
    const float* WZ = Wz + (size_t)col * INW + ED + lhi * 8;
    const float* WH = Wh + (size_t)col * INW + ED + lhi * 8;
    #pragma unroll
    for (int s = 0; s < 16; ++s) {
      float4 a, b; half8 w;
      a = *(const float4*)(WR + s * 32); b = *(const float4*)(WR + s * 32 + 4);
      w[0]=(_Float16)a.x; w[1]=(_Float16)a.y; w[2]=(_Float16)a.z; w[3]=(_Float16)a.w;
      w[4]=(_Float16)b.x; w[5]=(_Float16)b.y; w[6]=(_Float16)b.z; w[7]=(_Float16)b.w;
      wfR[s] = w;
      a = *(const float4*)(WZ + s * 32); b = *(const float4*)(WZ + s * 32 + 4);
      w[0]=(_Float16)a.x; w[1]=(_Float16)a.y; w[2]=(_Float16)a.z; w[3]=(_Float16)a.w;
      w[4]=(_Float16)b.x; w[5]=(_Float16)b.y; w[6]=(_Float16)b.z; w[7]=(_Float16)b.w;
      wfZ[s] = w;
      a = *(const float4*)(WH + s * 32); b = *(const float4*)(WH + s * 32 + 4);
      w[0]=(_Float16)a.x; w[1]=(_Float16)a.y; w[2]=(_Float16)a.z; w[3]=(_Float16)a.w;
      w[4]=(_Float16)b.x; w[5]=(_Float16)b.y; w[6]=(_Float16)b.z; w[7]=(_Float16)b.w;
      wfH[s] = w;
    }
  }

  // XG values for step 0 (prefetched; later steps prefetched inside the loop)
  float xgR[4], xgZ[4], xgH[4];
  #pragma unroll
  for (int q = 0; q < 4; ++q) {
    const int b = wv * 16 + lhi * 4 + q;
    const float* xp = XG + (size_t)b * NG + col;
    xgR[q] = xp[0]; xgZ[q] = xp[512]; xgH[q] = xp[1024];
  }

  unsigned epoch = 0;
  for (int t = 0; t < SQ; ++t) {
    // ---- phase A: preR/preZ = h @ W{r,z}h^T ; sigmoid -> uF (agent), z32 (private) ----
    {
      half8 ha[16];
      #pragma unroll
      for (int s = 0; s < 16; ++s)
        ha[s] = ldg_agent16(hF + (size_t)mrow * HD + s * 32 + lhi * 8);
      f32x4 accR = {}, accZ = {};
      #pragma unroll
      for (int s = 0; s < 16; ++s) {
        accR = __builtin_amdgcn_mfma_f32_16x16x32_f16(ha[s], wfR[s], accR, 0, 0, 0);
        accZ = __builtin_amdgcn_mfma_f32_16x16x32_f16(ha[s], wfZ[s], accZ, 0, 0, 0);
      }
      #pragma unroll
      for (int q = 0; q < 4; ++q) {
        const int b = wv * 16 + lhi * 4 + q;
        const float preR = accR[q] + xgR[q];
        const float r  = 1.0f / (1.0f + __expf(-preR));
        const float uv = r * h32[(size_t)b * HD + col];
        const _Float16 uh = (_Float16)uv;
        const unsigned short ub = __builtin_bit_cast(unsigned short, uh);
        const unsigned short ob = (unsigned short)__shfl_xor((int)ub, 1);
        if (!(l15 & 1)) {
          const unsigned wrd = (unsigned)ub | ((unsigned)ob << 16);
          __hip_atomic_store((unsigned*)(uF + (size_t)b * HD + col), wrd,
                             __ATOMIC_RELAXED, __HIP_MEMORY_SCOPE_AGENT);
        }
        const float preZ = accZ[q] + xgZ[q];
        z32[(size_t)b * HD + col] = 1.0f / (1.0f + __expf(-preZ));
      }
    }
    ++epoch; gridbar(flags, epoch, wg);

    // ---- phase B: pre = u @ Whh^T ; tanh + combine -> h32 (private), hF (agent) ----
    {
      half8 ua[16];
      #pragma unroll
      for (int s = 0; s < 16; ++s)
        ua[s] = ldg_agent16(uF + (size_t)mrow * HD + s * 32 + lhi * 8);
      f32x4 acc = {};
      #pragma unroll
      for (int s = 0; s < 16; ++s)
        acc = __builtin_amdgcn_mfma_f32_16x16x32_f16(ua[s], wfH[s], acc, 0, 0, 0);

      // prefetch next step's XG (overlaps epilogue + barrier drain)
      float nR[4] = {0,0,0,0}, nZ[4] = {0,0,0,0}, nH[4] = {0,0,0,0};
      if (t + 1 < SQ) {
        #pragma unroll
        for (int q = 0; q < 4; ++q) {
          const int b = wv * 16 + lhi * 4 + q;
          const float* xp = XG + (size_t)(t + 1) * BA * NG + (size_t)b * NG + col;
          nR[q] = xp[0]; nZ[q] = xp[512]; nH[q] = xp[1024];
        }
      }

      #pragma unroll
      for (int q = 0; q < 4; ++q) {
        const int b = wv * 16 + lhi * 4 + q;
        const float pre = acc[q] + xgH[q];
        const float e  = __expf(2.0f * pre);          // tanh, inf-safe
        const float hc = 1.0f - 2.0f / (e + 1.0f);
        const float z  = z32[(size_t)b * HD + col];
        const float ho = h32[(size_t)b * HD + col];
        const float hn = z * ho + (1.0f - z) * hc;
        h32[(size_t)b * HD + col] = hn;
        Habf[(size_t)(t * BA + b) * HD + col] = f2bf(hn);
        const _Float16 hh = (_Float16)hn;
        const unsigned short hb = __builtin_bit_cast(unsigned short, hh);
        const unsigned short hob = (unsigned short)__shfl_xor((int)hb, 1);
        if (!(l15 & 1)) {
          const unsigned wrd = (unsigned)hb | ((unsigned)hob << 16);
          __hip_atomic_store((unsigned*)(hF + (size_t)b * HD + col), wrd,
                             __ATOMIC_RELAXED, __HIP_MEMORY_SCOPE_AGENT);
        }
        if (t == SQ - 1) outT[col * BA + b] = hn;
      }
      #pragma unroll
      for (int q = 0; q < 4; ++q) { xgR[q] = nR[q]; xgZ[q] = nZ[q]; xgH[q] = nH[q]; }
    }
    ++epoch; gridbar(flags, epoch, wg);
  }
}

// ---------------- final output GEMM: Y = Habf @ W^T + b  (bf16 MFMA, fp32 out) ----------------
__global__ __launch_bounds__(256) void out_gemm_kernel(
    const unsigned short* __restrict__ A,  // 8192 x 512 bf16
    const float* __restrict__ Bw,          // 32000 x 512 f32
    const float* __restrict__ bias,        // 32000
    float* __restrict__ Y)                 // 8192 x 32000
{
  __shared__ unsigned short As[128 * 32];
  __shared__ unsigned short Bs[128 * 32];
  const int bid = blockIdx.x;
  const int tn = bid % 250, tm = bid / 250;
  const int tid = threadIdx.x;
  const int wave = tid >> 6, lane = tid & 63;
  const int wm = wave >> 1, wn = wave & 1;
  const int l15 = lane & 15, lhi = lane >> 4;
  f32x4 acc[4][4] = {};

  for (int k0 = 0; k0 < 512; k0 += 32) {
    #pragma unroll
    for (int it = 0; it < 2; ++it) {
      const int ss  = tid + it * 256;
      const int row = ss >> 2;
      const int c8  = (ss & 3) << 3;
      *(uint4*)(As + row * 32 + c8) =
          *(const uint4*)(A + (size_t)(tm * 128 + row) * 512 + k0 + c8);
      const float4 b0 = *(const float4*)(Bw + (size_t)(tn * 128 + row) * 512 + k0 + c8);
      const float4 b1 = *(const float4*)(Bw + (size_t)(tn * 128 + row) * 512 + k0 + c8 + 4);
      union { unsigned short h[8]; uint4 u; } cv;
      cv.h[0] = f2bf(b0.x); cv.h[1] = f2bf(b0.y); cv.h[2] = f2bf(b0.z); cv.h[3] = f2bf(b0.w);
      cv.h[4] = f2bf(b1.x); cv.h[5] = f2bf(b1.y); cv.h[6] = f2bf(b1.z); cv.h[7] = f2bf(b1.w);
      *(uint4*)(Bs + row * 32 + c8) = cv.u;
    }
    __syncthreads();
    sh8 af[4], bfr[4];
    #pragma unroll
    for (int mi = 0; mi < 4; ++mi)
      af[mi] = *(const sh8*)(As + (wm * 64 + mi * 16 + l15) * 32 + lhi * 8);
    #pragma unroll
    for (int ni = 0; ni < 4; ++ni)
      bfr[ni] = *(const sh8*)(Bs + (wn * 64 + ni * 16 + l15) * 32 + lhi * 8);
    #pragma unroll
    for (int mi = 0; mi < 4; ++mi)
      #pragma unroll
      for (int ni = 0; ni < 4; ++ni)
        acc[mi][ni] = __builtin_amdgcn_mfma_f32_16x16x32_bf16(af[mi], bfr[ni], acc[mi][ni], 0, 0, 0);
    __syncthreads();
  }

  #pragma unroll
  for (int ni = 0; ni < 4; ++ni) {
    const int col = tn * 128 + wn * 64 + ni * 16 + l15;
    const float bv = bias[col];
    #pragma unroll
    for (int mi = 0; mi < 4; ++mi) {
      const int row0 = tm * 128 + wm * 64 + mi * 16 + lhi * 4;
      #pragma unroll
      for (int q = 0; q < 4; ++q)
        Y[(size_t)(row0 + q) * VSZ + col] = acc[mi][ni][q] + bv;
    }
  }
}

extern "C" void kernel_launch(void* const* d_in, const int* in_sizes, int n_in,
                              void* d_out, int out_size, void* d_ws, size_t ws_size,
                              hipStream_t stream)
{
  const int*   x   = (const int*)  d_in[0];
  const float* emb = (const float*)d_in[1];
  const float* Wr  = (const float*)d_in[2];
  const float* Br  = (const float*)d_in[3];
  const float* Wz  = (const float*)d_in[4];
  const float* Bz  = (const float*)d_in[5];
  const float* Wh  = (const float*)d_in[6];
  const float* Bh  = (const float*)d_in[7];
  const float* W   = (const float*)d_in[8];
  const float* bo  = (const float*)d_in[9];
  float* out = (float*)d_out;

  char* ws = (char*)d_ws;
  float*          h32   = (float*)(ws);                    // 128 KiB [64][512]
  float*          z32   = (float*)(ws + 131072);           // 128 KiB [64][512]
  _Float16*       hF    = (_Float16*)(ws + 262144);        //  64 KiB [64][512]
  _Float16*       uF    = (_Float16*)(ws + 327680);        //  64 KiB [64][512]
  unsigned*       flags = (unsigned*)(ws + 393216);        //   4 KiB barrier flags
  unsigned short* Habf  = (unsigned short*)(ws + 397312);  //   8 MiB bf16 h history

  // XG (pre-projection) overlays d_out; dead before out_gemm writes Y.
  float* XG   = out;                  // [8192][1536]
  float* outT = out + 262144000ll;    // hT.T region

  // zero h32, z32, hF, uF, barrier flags (deterministic across graph replays)
  (void)hipMemsetAsync(ws, 0, 397312 + 4096, stream);

  proj_kernel<<<dim3(24, 128), 256, 0, stream>>>(x, emb, Wr, Br, Wz, Bz, Wh, Bh, XG);
  recur_kernel<<<NWG, 256, 0, stream>>>(XG, Wr, Wz, Wh, h32, z32, hF, uF, Habf, outT, flags);
  out_gemm_kernel<<<16000, 256, 0, stream>>>(Habf, W, bo, out);
}